// Round 5
// baseline (244.961 us; speedup 1.0000x reference)
//
#include <hip/hip_runtime.h>
#include <math.h>

#define B_  2
#define S_  2048
#define D_  1024
#define H_  16
#define DH_ 64
#define M_  (B_*S_)   // 4096 rows

typedef short v8s  __attribute__((ext_vector_type(8)));
typedef float v4f  __attribute__((ext_vector_type(4)));
typedef float f32x16 __attribute__((ext_vector_type(16)));
typedef unsigned short u16;

__device__ __forceinline__ u16 f2bf(float f) {          // RTNE
    unsigned u = __float_as_uint(f);
    u = u + 0x7FFFu + ((u >> 16) & 1u);
    return (u16)(u >> 16);
}
__device__ __forceinline__ u16 f2bf_t(float f) {        // truncate (P only)
    return (u16)(__float_as_uint(f) >> 16);
}

// ---------------------------------------------------------------------------
// Convert fp32 -> bf16, 8 elems/thread. y picks query/key/value.
// ---------------------------------------------------------------------------
__global__ __launch_bounds__(256)
void cvt_bf16_kernel(const float* __restrict__ X0, const float* __restrict__ X1,
                     const float* __restrict__ X2, u16* __restrict__ Y)
{
    const float* X = (blockIdx.y == 0) ? X0 : (blockIdx.y == 1) ? X1 : X2;
    u16* out = Y + (size_t)blockIdx.y * M_ * D_;
    const size_t i = ((size_t)blockIdx.x * 256 + threadIdx.x) * 8;
    float4 a = *(const float4*)&X[i];
    float4 b = *(const float4*)&X[i + 4];
    u16 tmp[8];
    tmp[0] = f2bf(a.x); tmp[1] = f2bf(a.y); tmp[2] = f2bf(a.z); tmp[3] = f2bf(a.w);
    tmp[4] = f2bf(b.x); tmp[5] = f2bf(b.y); tmp[6] = f2bf(b.z); tmp[7] = f2bf(b.w);
    *(v8s*)&out[i] = *(v8s*)&tmp[0];
}

// ---------------------------------------------------------------------------
// Transpose + convert weights: W[k][n] f32 -> Wt[n][k] bf16 (3 matrices).
// ---------------------------------------------------------------------------
__global__ __launch_bounds__(256)
void transpose_w_kernel(const float* __restrict__ W0, const float* __restrict__ W1,
                        const float* __restrict__ W2, u16* __restrict__ WtAll)
{
    __shared__ u16 TS[64][66];
    const float* W = (blockIdx.z == 0) ? W0 : (blockIdx.z == 1) ? W1 : W2;
    u16* out = WtAll + (size_t)blockIdx.z * D_ * D_;
    const int k0 = blockIdx.x * 64;
    const int n0 = blockIdx.y * 64;
    const int t = threadIdx.x;
    const int r = t >> 2, c = t & 3;

    #pragma unroll
    for (int u = 0; u < 4; ++u) {
        int nc = (c + 4 * u) * 4;
        float4 v = *(const float4*)&W[(size_t)(k0 + r) * D_ + n0 + nc];
        TS[r][nc + 0] = f2bf(v.x); TS[r][nc + 1] = f2bf(v.y);
        TS[r][nc + 2] = f2bf(v.z); TS[r][nc + 3] = f2bf(v.w);
    }
    __syncthreads();
    u16 tmp[16];
    #pragma unroll
    for (int u = 0; u < 16; ++u) tmp[u] = TS[c * 16 + u][r];
    u16* dst = &out[(size_t)(n0 + r) * D_ + k0 + c * 16];
    *(v8s*)&dst[0] = *(v8s*)&tmp[0];
    *(v8s*)&dst[8] = *(v8s*)&tmp[8];
}

// ---------------------------------------------------------------------------
// Fused QKV projection, 32x32x16 MFMA, BK=64, global_load_lds staging
// (linear LDS dest, source-swizzled chunks, matching swizzled ds_read).
// 128x128 tile, 4 waves, each owns a 64x64 wave-tile (2x2 of 32x32 mfma).
// z==0/1 write Qh/Kh head-major [B,H,S,DH]; z==2 writes Vt [B,H,DH,S].
// ---------------------------------------------------------------------------
__global__ __launch_bounds__(256)
void qkv_gemm_kernel(const u16* __restrict__ XbfAll, const u16* __restrict__ WtAll,
                     const float* __restrict__ bq, const float* __restrict__ bk2,
                     const float* __restrict__ bv2,
                     u16* __restrict__ Qh, u16* __restrict__ Kh, u16* __restrict__ Vt)
{
    __shared__ u16 SA[128 * 64];
    __shared__ u16 SB[128 * 64];

    const int z = blockIdx.z;
    const u16* X  = XbfAll + (size_t)z * M_ * D_;
    const u16* Wt = WtAll  + (size_t)z * D_ * D_;
    const float* bias = (z == 0) ? bq : (z == 1) ? bk2 : bv2;

    const int t = threadIdx.x;
    const int lane = t & 63;
    const int w = t >> 6;
    const int l31 = lane & 31;
    const int half = lane >> 5;
    const int wr = (w >> 1) * 64;
    const int wc = (w & 1) * 64;
    const int row0 = blockIdx.y * 128;
    const int col0 = blockIdx.x * 128;

    f32x16 acc[2][2];
    #pragma unroll
    for (int mb = 0; mb < 2; ++mb)
        #pragma unroll
        for (int nb = 0; nb < 2; ++nb)
            acc[mb][nb] = (f32x16)(0.0f);

    // staging: thread t, call c: row = c*32 + (t>>3), phys 16B-chunk = t&7
    const int srow = t >> 3;
    const int pch  = t & 7;

    for (int k0 = 0; k0 < D_; k0 += 64) {
        __syncthreads();   // all waves done reading LDS from previous iter
        #pragma unroll
        for (int c = 0; c < 4; ++c) {
            const int r = c * 32 + srow;
            const int lch = pch ^ (r & 7);          // source-side swizzle
            const u16* asrc = &X [(size_t)(row0 + r) * D_ + k0 + lch * 8];
            const u16* bsrc = &Wt[(size_t)(col0 + r) * D_ + k0 + lch * 8];
            __builtin_amdgcn_global_load_lds(
                (const __attribute__((address_space(1))) void*)asrc,
                (__attribute__((address_space(3))) void*)&SA[r * 64 + pch * 8],
                16, 0, 0);
            __builtin_amdgcn_global_load_lds(
                (const __attribute__((address_space(1))) void*)bsrc,
                (__attribute__((address_space(3))) void*)&SB[r * 64 + pch * 8],
                16, 0, 0);
        }
        __syncthreads();   // vmcnt drained before barrier

        #pragma unroll
        for (int ks = 0; ks < 4; ++ks) {
            v8s av[2], bv[2];
            #pragma unroll
            for (int mb = 0; mb < 2; ++mb) {
                const int r = wr + mb * 32 + l31;
                const int ch = (ks * 2 + half) ^ (r & 7);
                av[mb] = *(const v8s*)&SA[r * 64 + ch * 8];
            }
            #pragma unroll
            for (int nb = 0; nb < 2; ++nb) {
                const int r = wc + nb * 32 + l31;
                const int ch = (ks * 2 + half) ^ (r & 7);
                bv[nb] = *(const v8s*)&SB[r * 64 + ch * 8];
            }
            #pragma unroll
            for (int mb = 0; mb < 2; ++mb)
                #pragma unroll
                for (int nb = 0; nb < 2; ++nb)
                    acc[mb][nb] = __builtin_amdgcn_mfma_f32_32x32x16_bf16(
                        av[mb], bv[nb], acc[mb][nb], 0, 0, 0);
        }
    }

    // epilogue: +bias, bf16, scatter. C/D: col=lane&31, row=(r&3)+8*(r>>2)+4*half
    #pragma unroll
    for (int nb = 0; nb < 2; ++nb) {
        const int col = col0 + wc + nb * 32 + l31;
        const float bb = bias[col];
        const int h = col >> 6, d = col & 63;
        #pragma unroll
        for (int mb = 0; mb < 2; ++mb) {
            #pragma unroll
            for (int rg = 0; rg < 16; ++rg) {
                const int row = row0 + wr + mb * 32 + (rg & 3) + 8 * (rg >> 2) + 4 * half;
                const int b = row >> 11, s = row & (S_ - 1);
                const u16 o = f2bf(acc[mb][nb][rg] + bb);
                if (z == 0)
                    Qh[(((size_t)(b * H_ + h)) * S_ + s) * DH_ + d] = o;
                else if (z == 1)
                    Kh[(((size_t)(b * H_ + h)) * S_ + s) * DH_ + d] = o;
                else
                    Vt[(((size_t)(b * H_ + h)) * DH_ + d) * S_ + s] = o;
            }
        }
    }
}

// ---------------------------------------------------------------------------
// Flash attention, bf16 MFMA, max-free softmax (scores bounded; masked keys
// underflow exp2 to 0). K/V XOR-swizzled in LDS; P per-wave in LDS.
// ---------------------------------------------------------------------------
__global__ __launch_bounds__(256)
void attn_kernel(const u16* __restrict__ Qh, const u16* __restrict__ Kh,
                 const u16* __restrict__ Vt, const int* __restrict__ mask,
                 float* __restrict__ Hout)
{
    __shared__ u16 Ks[64][64];
    __shared__ u16 Vs[64][64];
    __shared__ u16 Ps[4][16][64];
    __shared__ float mb[64];

    const int t = threadIdx.x;
    const int lane = t & 63;
    const int w = t >> 6;
    const int g = lane >> 4;
    const int l15 = lane & 15;
    const int bh = blockIdx.y;
    const int b = bh >> 4;
    const int h = bh & 15;
    const int q0 = blockIdx.x * 64;

    const float SC = 0.18033688011112042f;    // 0.125 * log2(e)
    const float MBIAS = -14426.950408889634f; // -10000 * log2(e)

    v8s aq[2];
    {
        const u16* qb = Qh + ((size_t)bh * S_ + q0 + w * 16 + l15) * DH_;
        aq[0] = *(const v8s*)&qb[g * 8];
        aq[1] = *(const v8s*)&qb[32 + g * 8];
    }

    float lsum[4] = {0.f, 0.f, 0.f, 0.f};
    v4f Of[4];
    #pragma unroll
    for (int j = 0; j < 4; ++j) Of[j] = (v4f){0.f, 0.f, 0.f, 0.f};

    const int sk = t >> 3;     // 0..31
    const int sj = t & 7;      // 16B chunk within row
    const int swz_s = (sj ^ (sk & 7)) * 8;

    for (int kt = 0; kt < S_ / 64; ++kt) {
        const int kbase = kt * 64;
        const u16* ksrc0 = Kh + ((size_t)bh * S_ + kbase + sk) * DH_ + sj * 8;
        const u16* ksrc1 = Kh + ((size_t)bh * S_ + kbase + sk + 32) * DH_ + sj * 8;
        v8s kr0 = *(const v8s*)ksrc0;
        v8s kr1 = *(const v8s*)ksrc1;
        const u16* vsrc0 = Vt + ((size_t)bh * DH_ + sk) * S_ + kbase + sj * 8;
        const u16* vsrc1 = Vt + ((size_t)bh * DH_ + sk + 32) * S_ + kbase + sj * 8;
        v8s vr0 = *(const v8s*)vsrc0;
        v8s vr1 = *(const v8s*)vsrc1;
        int mv = 0;
        if (t < 64) mv = mask[b * S_ + kbase + t];

        __syncthreads();
        *(v8s*)&Ks[sk][swz_s]      = kr0;
        *(v8s*)&Ks[sk + 32][swz_s] = kr1;
        *(v8s*)&Vs[sk][swz_s]      = vr0;
        *(v8s*)&Vs[sk + 32][swz_s] = vr1;
        if (t < 64) mb[t] = mv ? 0.0f : MBIAS;
        __syncthreads();

        // ---- scores: QK^T via MFMA ----
        v4f sc4[4];
        #pragma unroll
        for (int j = 0; j < 4; ++j) sc4[j] = (v4f){0.f, 0.f, 0.f, 0.f};
        #pragma unroll
        for (int j = 0; j < 4; ++j) {
            const int kcol = j * 16 + l15;
            const int sx = kcol & 7;
            v8s bk0 = *(const v8s*)&Ks[kcol][((0 * 4 + g) ^ sx) * 8];
            v8s bk1 = *(const v8s*)&Ks[kcol][((1 * 4 + g) ^ sx) * 8];
            sc4[j] = __builtin_amdgcn_mfma_f32_16x16x32_bf16(aq[0], bk0, sc4[j], 0, 0, 0);
            sc4[j] = __builtin_amdgcn_mfma_f32_16x16x32_bf16(aq[1], bk1, sc4[j], 0, 0, 0);
        }
        float mbj[4];
        #pragma unroll
        for (int j = 0; j < 4; ++j) mbj[j] = mb[j * 16 + l15];

        // ---- max-free softmax ----
        #pragma unroll
        for (int i = 0; i < 4; ++i) {
            float p0 = __builtin_amdgcn_exp2f(fmaf(sc4[0][i], SC, mbj[0]));
            float p1 = __builtin_amdgcn_exp2f(fmaf(sc4[1][i], SC, mbj[1]));
            float p2 = __builtin_amdgcn_exp2f(fmaf(sc4[2][i], SC, mbj[2]));
            float p3 = __builtin_amdgcn_exp2f(fmaf(sc4[3][i], SC, mbj[3]));
            lsum[i] += (p0 + p1) + (p2 + p3);
            const int q = g * 4 + i;
            const int swz = 8 * (q & 7);
            Ps[w][q][(0 * 16 + l15) ^ swz] = f2bf_t(p0);
            Ps[w][q][(1 * 16 + l15) ^ swz] = f2bf_t(p1);
            Ps[w][q][(2 * 16 + l15) ^ swz] = f2bf_t(p2);
            Ps[w][q][(3 * 16 + l15) ^ swz] = f2bf_t(p3);
        }

        // ---- O += P @ V ----
        const int sq = l15 & 7;
        v8s pa0 = *(const v8s*)&Ps[w][l15][((0 + g) ^ sq) * 8];
        v8s pa1 = *(const v8s*)&Ps[w][l15][((4 + g) ^ sq) * 8];
        #pragma unroll
        for (int j = 0; j < 4; ++j) {
            const int dcol = j * 16 + l15;
            const int sx = dcol & 7;
            v8s bv0 = *(const v8s*)&Vs[dcol][((0 + g) ^ sx) * 8];
            v8s bv1 = *(const v8s*)&Vs[dcol][((4 + g) ^ sx) * 8];
            Of[j] = __builtin_amdgcn_mfma_f32_16x16x32_bf16(pa0, bv0, Of[j], 0, 0, 0);
            Of[j] = __builtin_amdgcn_mfma_f32_16x16x32_bf16(pa1, bv1, Of[j], 0, 0, 0);
        }
    }

    // ---- epilogue ----
    #pragma unroll
    for (int i = 0; i < 4; ++i) {
        lsum[i] += __shfl_xor(lsum[i], 1, 64);
        lsum[i] += __shfl_xor(lsum[i], 2, 64);
        lsum[i] += __shfl_xor(lsum[i], 4, 64);
        lsum[i] += __shfl_xor(lsum[i], 8, 64);
    }
    float inv[4];
    #pragma unroll
    for (int i = 0; i < 4; ++i) inv[i] = 1.0f / lsum[i];
    #pragma unroll
    for (int j = 0; j < 4; ++j) {
        #pragma unroll
        for (int i = 0; i < 4; ++i) {
            int q = q0 + w * 16 + g * 4 + i;
            Hout[((size_t)(b * S_ + q)) * D_ + h * DH_ + j * 16 + l15] = Of[j][i] * inv[i];
        }
    }
}

// ---------------------------------------------------------------------------
// Residual + LayerNorm
// ---------------------------------------------------------------------------
__global__ __launch_bounds__(256)
void ln_kernel(const float* __restrict__ query, const float* __restrict__ Hout,
               const float* __restrict__ gamma, const float* __restrict__ beta,
               float* __restrict__ out)
{
    __shared__ float ws1[4], ws2[4];
    const int row = blockIdx.x;
    const int tid = threadIdx.x;
    const size_t base = (size_t)row * D_ + tid * 4;

    float4 xq = *(const float4*)&query[base];
    float4 xh = *(const float4*)&Hout[base];
    float x[4] = { xq.x + xh.x, xq.y + xh.y, xq.z + xh.z, xq.w + xh.w };

    float sum = x[0] + x[1] + x[2] + x[3];
    float sq  = x[0]*x[0] + x[1]*x[1] + x[2]*x[2] + x[3]*x[3];
    #pragma unroll
    for (int off = 32; off >= 1; off >>= 1) {
        sum += __shfl_down(sum, off, 64);
        sq  += __shfl_down(sq,  off, 64);
    }
    if ((tid & 63) == 0) { ws1[tid >> 6] = sum; ws2[tid >> 6] = sq; }
    __syncthreads();
    sum = ws1[0] + ws1[1] + ws1[2] + ws1[3];
    sq  = ws2[0] + ws2[1] + ws2[2] + ws2[3];

    const float u    = sum * (1.0f / D_);
    const float var  = sq * (1.0f / D_) - u * u;
    const float rstd = rsqrtf(var + 1e-12f);

    float4 gv = *(const float4*)&gamma[tid * 4];
    float4 bv = *(const float4*)&beta[tid * 4];
    float4 o;
    o.x = gv.x * (x[0] - u) * rstd + bv.x;
    o.y = gv.y * (x[1] - u) * rstd + bv.y;
    o.z = gv.z * (x[2] - u) * rstd + bv.z;
    o.w = gv.w * (x[3] - u) * rstd + bv.w;
    *(float4*)&out[base] = o;
}

// ---------------------------------------------------------------------------
extern "C" void kernel_launch(void* const* d_in, const int* in_sizes, int n_in,
                              void* d_out, int out_size, void* d_ws, size_t ws_size,
                              hipStream_t stream)
{
    const float* query = (const float*)d_in[0];
    const float* key   = (const float*)d_in[1];
    const float* value = (const float*)d_in[2];
    const int*   mask  = (const int*)d_in[3];
    const float* Wq    = (const float*)d_in[4];
    const float* bq    = (const float*)d_in[5];
    const float* Wk    = (const float*)d_in[6];
    const float* bk    = (const float*)d_in[7];
    const float* Wv    = (const float*)d_in[8];
    const float* bv    = (const float*)d_in[9];
    const float* gamma = (const float*)d_in[10];
    const float* beta  = (const float*)d_in[11];
    float* out = (float*)d_out;

    char* ws = (char*)d_ws;
    u16* Xbf = (u16*)ws;                      ws += (size_t)3 * M_ * D_ * sizeof(u16);  // 24 MB
    u16* Wt  = (u16*)ws;                      ws += (size_t)3 * D_ * D_ * sizeof(u16);  //  6 MB
    u16* Qh  = (u16*)ws;                      ws += (size_t)M_ * D_ * sizeof(u16);      //  8 MB
    u16* Kh  = (u16*)ws;                      ws += (size_t)M_ * D_ * sizeof(u16);      //  8 MB
    u16* Vt  = (u16*)ws;                      ws += (size_t)M_ * D_ * sizeof(u16);      //  8 MB
    float* Ho = (float*)ws;                                                            // 16 MB

    cvt_bf16_kernel<<<dim3(M_ * D_ / 2048, 3), 256, 0, stream>>>(query, key, value, Xbf);
    transpose_w_kernel<<<dim3(16, 16, 3), 256, 0, stream>>>(Wq, Wk, Wv, Wt);
    qkv_gemm_kernel<<<dim3(D_ / 128, M_ / 128, 3), 256, 0, stream>>>(
        Xbf, Wt, bq, bk, bv, Qh, Kh, Vt);
    attn_kernel<<<dim3(S_ / 64, B_ * H_), 256, 0, stream>>>(Qh, Kh, Vt, mask, Ho);
    ln_kernel<<<M_, 256, 0, stream>>>(query, Ho, gamma, beta, out);
}

// Round 7
// 227.934 us; speedup vs baseline: 1.0747x; 1.0747x over previous
//
#include <hip/hip_runtime.h>
#include <math.h>

#define B_  2
#define S_  2048
#define D_  1024
#define H_  16
#define DH_ 64
#define M_  (B_*S_)   // 4096 rows

typedef short v8s  __attribute__((ext_vector_type(8)));
typedef float v4f  __attribute__((ext_vector_type(4)));
typedef float f32x16 __attribute__((ext_vector_type(16)));
typedef unsigned short u16;
typedef unsigned int u32;

__device__ __forceinline__ u16 f2bf(float f) {          // RTNE
    u32 u = __float_as_uint(f);
    u = u + 0x7FFFu + ((u >> 16) & 1u);
    return (u16)(u >> 16);
}

// ---------------------------------------------------------------------------
// Convert fp32 -> bf16, 8 elems/thread. y picks query/key/value.
// ---------------------------------------------------------------------------
__global__ __launch_bounds__(256)
void cvt_bf16_kernel(const float* __restrict__ X0, const float* __restrict__ X1,
                     const float* __restrict__ X2, u16* __restrict__ Y)
{
    const float* X = (blockIdx.y == 0) ? X0 : (blockIdx.y == 1) ? X1 : X2;
    u16* out = Y + (size_t)blockIdx.y * M_ * D_;
    const size_t i = ((size_t)blockIdx.x * 256 + threadIdx.x) * 8;
    float4 a = *(const float4*)&X[i];
    float4 b = *(const float4*)&X[i + 4];
    u16 tmp[8];
    tmp[0] = f2bf(a.x); tmp[1] = f2bf(a.y); tmp[2] = f2bf(a.z); tmp[3] = f2bf(a.w);
    tmp[4] = f2bf(b.x); tmp[5] = f2bf(b.y); tmp[6] = f2bf(b.z); tmp[7] = f2bf(b.w);
    *(v8s*)&out[i] = *(v8s*)&tmp[0];
}

// ---------------------------------------------------------------------------
// Transpose + convert weights: W[k][n] f32 -> Wt[n][k] bf16 (3 matrices).
// ---------------------------------------------------------------------------
__global__ __launch_bounds__(256)
void transpose_w_kernel(const float* __restrict__ W0, const float* __restrict__ W1,
                        const float* __restrict__ W2, u16* __restrict__ WtAll)
{
    __shared__ u16 TS[64][66];
    const float* W = (blockIdx.z == 0) ? W0 : (blockIdx.z == 1) ? W1 : W2;
    u16* out = WtAll + (size_t)blockIdx.z * D_ * D_;
    const int k0 = blockIdx.x * 64;
    const int n0 = blockIdx.y * 64;
    const int t = threadIdx.x;
    const int r = t >> 2, c = t & 3;

    #pragma unroll
    for (int u = 0; u < 4; ++u) {
        int nc = (c + 4 * u) * 4;
        float4 v = *(const float4*)&W[(size_t)(k0 + r) * D_ + n0 + nc];
        TS[r][nc + 0] = f2bf(v.x); TS[r][nc + 1] = f2bf(v.y);
        TS[r][nc + 2] = f2bf(v.z); TS[r][nc + 3] = f2bf(v.w);
    }
    __syncthreads();
    u16 tmp[16];
    #pragma unroll
    for (int u = 0; u < 16; ++u) tmp[u] = TS[c * 16 + u][r];
    u16* dst = &out[(size_t)(n0 + r) * D_ + k0 + c * 16];
    *(v8s*)&dst[0] = *(v8s*)&tmp[0];
    *(v8s*)&dst[8] = *(v8s*)&tmp[8];
}

// ---------------------------------------------------------------------------
// Fused QKV projection, 32x32x16 MFMA, BK=64, global_load_lds staging
// (linear LDS dest, source-swizzled chunks, matching swizzled ds_read —
// rule #21: same involution on both sides). 128x128 tile, 4 waves.
// All outputs head-major bf16 [B,H,S,DH] (coalesced; V transposed later).
// ---------------------------------------------------------------------------
__global__ __launch_bounds__(256)
void qkv_gemm_kernel(const u16* __restrict__ XbfAll, const u16* __restrict__ WtAll,
                     const float* __restrict__ bq, const float* __restrict__ bk2,
                     const float* __restrict__ bv2,
                     u16* __restrict__ Qh, u16* __restrict__ Kh, u16* __restrict__ Vh)
{
    __shared__ u16 SA[128 * 64];
    __shared__ u16 SB[128 * 64];

    const int z = blockIdx.z;
    const u16* X  = XbfAll + (size_t)z * M_ * D_;
    const u16* Wt = WtAll  + (size_t)z * D_ * D_;
    const float* bias = (z == 0) ? bq : (z == 1) ? bk2 : bv2;
    u16* Y = (z == 0) ? Qh : (z == 1) ? Kh : Vh;

    const int t = threadIdx.x;
    const int lane = t & 63;
    const int w = t >> 6;
    const int l31 = lane & 31;
    const int half = lane >> 5;
    const int wr = (w >> 1) * 64;
    const int wc = (w & 1) * 64;
    const int row0 = blockIdx.y * 128;
    const int col0 = blockIdx.x * 128;

    f32x16 acc[2][2];
    #pragma unroll
    for (int mb = 0; mb < 2; ++mb)
        #pragma unroll
        for (int nb = 0; nb < 2; ++nb)
            acc[mb][nb] = (f32x16)(0.0f);

    const int srow = t >> 3;
    const int pch  = t & 7;

    for (int k0 = 0; k0 < D_; k0 += 64) {
        __syncthreads();
        #pragma unroll
        for (int c = 0; c < 4; ++c) {
            const int r = c * 32 + srow;
            const int lch = pch ^ (r & 7);          // source-side swizzle
            const u16* asrc = &X [(size_t)(row0 + r) * D_ + k0 + lch * 8];
            const u16* bsrc = &Wt[(size_t)(col0 + r) * D_ + k0 + lch * 8];
            __builtin_amdgcn_global_load_lds(
                (const __attribute__((address_space(1))) void*)asrc,
                (__attribute__((address_space(3))) void*)&SA[r * 64 + pch * 8],
                16, 0, 0);
            __builtin_amdgcn_global_load_lds(
                (const __attribute__((address_space(1))) void*)bsrc,
                (__attribute__((address_space(3))) void*)&SB[r * 64 + pch * 8],
                16, 0, 0);
        }
        __syncthreads();

        #pragma unroll
        for (int ks = 0; ks < 4; ++ks) {
            v8s av[2], bv[2];
            #pragma unroll
            for (int mb = 0; mb < 2; ++mb) {
                const int r = wr + mb * 32 + l31;
                const int ch = (ks * 2 + half) ^ (r & 7);
                av[mb] = *(const v8s*)&SA[r * 64 + ch * 8];
            }
            #pragma unroll
            for (int nb = 0; nb < 2; ++nb) {
                const int r = wc + nb * 32 + l31;
                const int ch = (ks * 2 + half) ^ (r & 7);
                bv[nb] = *(const v8s*)&SB[r * 64 + ch * 8];
            }
            #pragma unroll
            for (int mb = 0; mb < 2; ++mb)
                #pragma unroll
                for (int nb = 0; nb < 2; ++nb)
                    acc[mb][nb] = __builtin_amdgcn_mfma_f32_32x32x16_bf16(
                        av[mb], bv[nb], acc[mb][nb], 0, 0, 0);
        }
    }

    // epilogue: +bias, bf16. C/D: col=lane&31, row=(rg&3)+8*(rg>>2)+4*half
    #pragma unroll
    for (int nb = 0; nb < 2; ++nb) {
        const int col = col0 + wc + nb * 32 + l31;
        const float bb = bias[col];
        const int h = col >> 6, d = col & 63;
        #pragma unroll
        for (int mb = 0; mb < 2; ++mb) {
            #pragma unroll
            for (int rg = 0; rg < 16; ++rg) {
                const int row = row0 + wr + mb * 32 + (rg & 3) + 8 * (rg >> 2) + 4 * half;
                const int b = row >> 11, s = row & (S_ - 1);
                Y[(((size_t)(b * H_ + h)) * S_ + s) * DH_ + d] = f2bf(acc[mb][nb][rg] + bb);
            }
        }
    }
}

// ---------------------------------------------------------------------------
// Transpose V: Vh[b,h,s,d] bf16 -> Vt[b,h,d,s] bf16 (coalesced LDS tile)
// ---------------------------------------------------------------------------
__global__ __launch_bounds__(256)
void transpose_v_kernel(const u16* __restrict__ Vh, u16* __restrict__ Vt)
{
    __shared__ u16 TS[64][66];
    const int bh = blockIdx.y;
    const int s0 = blockIdx.x * 64;
    const int t = threadIdx.x;
    const int r = t >> 2, c = t & 3;

    {
        const u16* src = Vh + ((size_t)(bh * S_ + s0 + r)) * DH_ + c * 16;
        v8s a = *(const v8s*)&src[0];
        v8s b = *(const v8s*)&src[8];
        *(v8s*)&TS[r][c * 16]     = a;
        *(v8s*)&TS[r][c * 16 + 8] = b;
    }
    __syncthreads();
    u16 tmp[16];
    #pragma unroll
    for (int u = 0; u < 16; ++u) tmp[u] = TS[c * 16 + u][r];
    u16* dst = Vt + ((size_t)(bh * DH_ + r)) * S_ + s0 + c * 16;
    *(v8s*)&dst[0] = *(v8s*)&tmp[0];
    *(v8s*)&dst[8] = *(v8s*)&tmp[8];
}

// ---------------------------------------------------------------------------
// Flash attention, 32x32x16 MFMA, swapped QK^T (S^T = K x Q^T) so softmax is
// lane-local; P assembled in-register via cvt_pk_bf16 + permlane32_swap
// (T12). Mask via per-wave ballot word. Max-free softmax (masked keys -> 0).
// 4 waves x 32 q-rows = 128 q/block. K/V tiles XOR-swizzled in LDS.
// ---------------------------------------------------------------------------
__global__ __launch_bounds__(256)
void attn_kernel(const u16* __restrict__ Qh, const u16* __restrict__ Kh,
                 const u16* __restrict__ Vt, const int* __restrict__ mask,
                 float* __restrict__ Hout)
{
    __shared__ u16 Ks[64][64];   // [k][d], chunk-swizzled
    __shared__ u16 Vs[64][64];   // [d][k], chunk-swizzled
    __shared__ float lsq[4][32];

    const int t = threadIdx.x;
    const int lane = t & 63;
    const int w = t >> 6;
    const int l31 = lane & 31;
    const int half = lane >> 5;
    const int bh = blockIdx.y;
    const int b = bh >> 4;
    const int h = bh & 15;
    const int q0 = blockIdx.x * 128 + w * 32;     // wave's q base
    const float SC = 0.18033688011112042f;        // 0.125 * log2(e)

    // Q B-fragments (col=lane&31=q, k(d)=half*8+e, window step*16), one-time
    v8s qf[4];
    {
        const u16* qb = Qh + ((size_t)bh * S_ + q0 + l31) * DH_;
        #pragma unroll
        for (int sp = 0; sp < 4; ++sp)
            qf[sp] = *(const v8s*)&qb[sp * 16 + half * 8];
    }

    f32x16 O0 = (f32x16)(0.0f), O1 = (f32x16)(0.0f);
    float lsum = 0.0f;

    const int sk = t >> 3;     // 0..31
    const int sj = t & 7;      // 16B chunk
    const int swz = (sj ^ (sk & 7)) * 8;
    const int rsw = (l31 & 7); // read-side swizzle key (row&7)

    for (int kt = 0; kt < S_ / 64; ++kt) {
        const int kbase = kt * 64;
        // ---- global loads to regs ----
        v8s kr0 = *(const v8s*)&Kh[((size_t)bh * S_ + kbase + sk) * DH_ + sj * 8];
        v8s kr1 = *(const v8s*)&Kh[((size_t)bh * S_ + kbase + sk + 32) * DH_ + sj * 8];
        v8s vr0 = *(const v8s*)&Vt[((size_t)bh * DH_ + sk) * S_ + kbase + sj * 8];
        v8s vr1 = *(const v8s*)&Vt[((size_t)bh * DH_ + sk + 32) * S_ + kbase + sj * 8];
        const int mv = mask[b * S_ + kbase + lane];
        const unsigned long long mword = __ballot(mv != 0);

        __syncthreads();
        *(v8s*)&Ks[sk][swz]      = kr0;
        *(v8s*)&Ks[sk + 32][swz] = kr1;
        *(v8s*)&Vs[sk][swz]      = vr0;
        *(v8s*)&Vs[sk + 32][swz] = vr1;
        __syncthreads();

        // ---- S^T = K x Q^T : st0 rows k=0..31, st1 rows k=32..63 ----
        f32x16 st0 = (f32x16)(0.0f), st1 = (f32x16)(0.0f);
        #pragma unroll
        for (int sp = 0; sp < 4; ++sp) {
            const int ch = ((sp * 2 + half) ^ rsw) * 8;
            v8s k0 = *(const v8s*)&Ks[l31][ch];
            v8s k1 = *(const v8s*)&Ks[32 + l31][ch];
            st0 = __builtin_amdgcn_mfma_f32_32x32x16_bf16(k0, qf[sp], st0, 0, 0, 0);
            st1 = __builtin_amdgcn_mfma_f32_32x32x16_bf16(k1, qf[sp], st1, 0, 0, 0);
        }

        // ---- lane-local max-free softmax + mask (k_reg = crow(r,half)+32t) ----
        const u32 vs0 = ((u32)mword) >> (4 * half);
        const u32 vs1 = ((u32)(mword >> 32)) >> (4 * half);
        float p0[16], p1[16];
        #pragma unroll
        for (int r = 0; r < 16; ++r) {
            const int sh = (r & 3) + 8 * (r >> 2);
            float e0 = __builtin_amdgcn_exp2f(st0[r] * SC);
            float e1 = __builtin_amdgcn_exp2f(st1[r] * SC);
            p0[r] = ((vs0 >> sh) & 1u) ? e0 : 0.0f;
            p1[r] = ((vs1 >> sh) & 1u) ? e1 : 0.0f;
            lsum += p0[r] + p1[r];
        }

        // ---- pack P to bf16 pairs; permlane32_swap assembles PV A-frags ----
        u32 w0[8], w1[8];
        #pragma unroll
        for (int m = 0; m < 8; ++m) {
            asm("v_cvt_pk_bf16_f32 %0, %1, %2" : "=v"(w0[m]) : "v"(p0[2*m]), "v"(p0[2*m+1]));
            asm("v_cvt_pk_bf16_f32 %0, %1, %2" : "=v"(w1[m]) : "v"(p1[2*m]), "v"(p1[2*m+1]));
        }
        union PU { u32 u[4]; v8s v; };
        v8s pa[4];
        #pragma unroll
        for (int ksp = 0; ksp < 2; ++ksp) {
            {   // t=0: pa[ksp]
                u32 a  = w0[4*ksp],     bb = w0[4*ksp+2];
                u32 a2 = w0[4*ksp+1],   b2 = w0[4*ksp+3];
                asm("v_permlane32_swap_b32 %0, %1" : "+v"(a),  "+v"(bb));
                asm("v_permlane32_swap_b32 %0, %1" : "+v"(a2), "+v"(b2));
                PU pu; pu.u[0] = a; pu.u[1] = a2; pu.u[2] = bb; pu.u[3] = b2;
                pa[ksp] = pu.v;
            }
            {   // t=1: pa[2+ksp]
                u32 a  = w1[4*ksp],     bb = w1[4*ksp+2];
                u32 a2 = w1[4*ksp+1],   b2 = w1[4*ksp+3];
                asm("v_permlane32_swap_b32 %0, %1" : "+v"(a),  "+v"(bb));
                asm("v_permlane32_swap_b32 %0, %1" : "+v"(a2), "+v"(b2));
                PU pu; pu.u[0] = a; pu.u[1] = a2; pu.u[2] = bb; pu.u[3] = b2;
                pa[2 + ksp] = pu.v;
            }
        }

        // ---- O += P x V (A=P rows q, B=V^T rows d) ----
        #pragma unroll
        for (int ks = 0; ks < 4; ++ks) {
            const int ch = ((ks * 2 + half) ^ rsw) * 8;
            v8s b0 = *(const v8s*)&Vs[l31][ch];
            v8s b1 = *(const v8s*)&Vs[32 + l31][ch];
            O0 = __builtin_amdgcn_mfma_f32_32x32x16_bf16(pa[ks], b0, O0, 0, 0, 0);
            O1 = __builtin_amdgcn_mfma_f32_32x32x16_bf16(pa[ks], b1, O1, 0, 0, 0);
        }
    }

    // ---- epilogue: combine halves of lsum, distribute inv via per-wave LDS ----
    lsum += __shfl_xor(lsum, 32, 64);
    if (half == 0) lsq[w][l31] = 1.0f / lsum;
    // wave-coherent LDS: same-wave write->read, in-order; no barrier needed
    #pragma unroll
    for (int r = 0; r < 16; ++r) {
        const int qrow = (r & 3) + 8 * (r >> 2) + 4 * half;
        const float iv = lsq[w][qrow];
        float* dst = &Hout[((size_t)(b * S_ + q0 + qrow)) * D_ + h * DH_];
        dst[l31]      = O0[r] * iv;
        dst[32 + l31] = O1[r] * iv;
    }
}

// ---------------------------------------------------------------------------
// Residual + LayerNorm
// ---------------------------------------------------------------------------
__global__ __launch_bounds__(256)
void ln_kernel(const float* __restrict__ query, const float* __restrict__ Hout,
               const float* __restrict__ gamma, const float* __restrict__ beta,
               float* __restrict__ out)
{
    __shared__ float ws1[4], ws2[4];
    const int row = blockIdx.x;
    const int tid = threadIdx.x;
    const size_t base = (size_t)row * D_ + tid * 4;

    float4 xq = *(const float4*)&query[base];
    float4 xh = *(const float4*)&Hout[base];
    float x[4] = { xq.x + xh.x, xq.y + xh.y, xq.z + xh.z, xq.w + xh.w };

    float sum = x[0] + x[1] + x[2] + x[3];
    float sq  = x[0]*x[0] + x[1]*x[1] + x[2]*x[2] + x[3]*x[3];
    #pragma unroll
    for (int off = 32; off >= 1; off >>= 1) {
        sum += __shfl_down(sum, off, 64);
        sq  += __shfl_down(sq,  off, 64);
    }
    if ((tid & 63) == 0) { ws1[tid >> 6] = sum; ws2[tid >> 6] = sq; }
    __syncthreads();
    sum = ws1[0] + ws1[1] + ws1[2] + ws1[3];
    sq  = ws2[0] + ws2[1] + ws2[2] + ws2[3];

    const float u    = sum * (1.0f / D_);
    const float var  = sq * (1.0f / D_) - u * u;
    const float rstd = rsqrtf(var + 1e-12f);

    float4 gv = *(const float4*)&gamma[tid * 4];
    float4 bv = *(const float4*)&beta[tid * 4];
    float4 o;
    o.x = gv.x * (x[0] - u) * rstd + bv.x;
    o.y = gv.y * (x[1] - u) * rstd + bv.y;
    o.z = gv.z * (x[2] - u) * rstd + bv.z;
    o.w = gv.w * (x[3] - u) * rstd + bv.w;
    *(float4*)&out[base] = o;
}

// ---------------------------------------------------------------------------
extern "C" void kernel_launch(void* const* d_in, const int* in_sizes, int n_in,
                              void* d_out, int out_size, void* d_ws, size_t ws_size,
                              hipStream_t stream)
{
    const float* query = (const float*)d_in[0];
    const float* key   = (const float*)d_in[1];
    const float* value = (const float*)d_in[2];
    const int*   mask  = (const int*)d_in[3];
    const float* Wq    = (const float*)d_in[4];
    const float* bq    = (const float*)d_in[5];
    const float* Wk    = (const float*)d_in[6];
    const float* bk    = (const float*)d_in[7];
    const float* Wv    = (const float*)d_in[8];
    const float* bv    = (const float*)d_in[9];
    const float* gamma = (const float*)d_in[10];
    const float* beta  = (const float*)d_in[11];
    float* out = (float*)d_out;

    char* ws = (char*)d_ws;
    u16* Xbf = (u16*)ws;                      ws += (size_t)3 * M_ * D_ * sizeof(u16);  // 24 MB
    u16* Wt  = (u16*)ws;                      ws += (size_t)3 * D_ * D_ * sizeof(u16);  //  6 MB
    u16* Qh  = (u16*)ws;                      ws += (size_t)M_ * D_ * sizeof(u16);      //  8 MB
    u16* Kh  = (u16*)ws;                      ws += (size_t)M_ * D_ * sizeof(u16);      //  8 MB
    u16* Vh  = (u16*)ws;                      ws += (size_t)M_ * D_ * sizeof(u16);      //  8 MB
    u16* Vt  = (u16*)ws;                      ws += (size_t)M_ * D_ * sizeof(u16);      //  8 MB
    float* Ho = (float*)ws;                                                            // 16 MB

    cvt_bf16_kernel<<<dim3(M_ * D_ / 2048, 3), 256, 0, stream>>>(query, key, value, Xbf);
    transpose_w_kernel<<<dim3(16, 16, 3), 256, 0, stream>>>(Wq, Wk, Wv, Wt);
    qkv_gemm_kernel<<<dim3(D_ / 128, M_ / 128, 3), 256, 0, stream>>>(
        Xbf, Wt, bq, bk, bv, Qh, Kh, Vh);
    transpose_v_kernel<<<dim3(S_ / 64, B_ * H_), 256, 0, stream>>>(Vh, Vt);
    attn_kernel<<<dim3(S_ / 128, B_ * H_), 256, 0, stream>>>(Qh, Kh, Vt, mask, Ho);
    ln_kernel<<<M_, 256, 0, stream>>>(query, Ho, gamma, beta, out);
}